// Round 2
// baseline (2956.831 us; speedup 1.0000x reference)
//
#include <hip/hip_runtime.h>

// GNN_41051297415239: 2-layer GraphSAGE + linear skip on MI355X (gfx950)
// N=100000 nodes, E=1600000 edges, F_IN=64, HID=128, OUT=64
//
// Algebraic restructure:
//   h   = relu( [agg1/deg | x] @ [W1n ; W1r+Wl1] + (b1n+bl1) )   (K=128 GEMM)
//   p   = h @ W2n        (project BEFORE aggregating: 64-wide scatter)
//   out = agg(p)/deg + h @ (W2r+Wl2) + (b2n+bl2)
//
// Dtype robustness: device-side sniffers decide (a) edge_index int64 vs int32,
// (b) x/weights fp32 vs bf16. Prep kernels canonicalize x -> bf16 xb and
// weights -> combined transposed bf16 arrays, so the hot kernels are
// branch-free. Output store branches on the fp32 flag (in-dtype == out-dtype).

#define NN 100000
#define NE 1600000

typedef __attribute__((ext_vector_type(8))) __bf16 bf16x8;
typedef __attribute__((ext_vector_type(4))) float f32x4;

__device__ __forceinline__ float b2f(unsigned short u) {
    unsigned v = ((unsigned)u) << 16;
    float f;
    __builtin_memcpy(&f, &v, 4);
    return f;
}
__device__ __forceinline__ unsigned short f2b(float f) {
    unsigned u;
    __builtin_memcpy(&u, &f, 4);
    u += 0x7FFFu + ((u >> 16) & 1u);   // round-to-nearest-even
    return (unsigned short)(u >> 16);
}

// flags[0] = 1 if edge_index is int64; flags[1] = 1 if x/weights are fp32.
__global__ void sniff_kernel(const int* __restrict__ ei,
                             const unsigned int* __restrict__ xw,
                             int* __restrict__ flags) {
    __shared__ int s_or[256];
    __shared__ int s_cnt[256];
    int tid = threadIdx.x;
    // int64 check: odd 32-bit words are high halves (0 for nonneg < 2^31 ids)
    s_or[tid] = ei[2 * tid + 1];
    // fp32 check: low 16 bits of an fp32 word, viewed as bf16, has a uniform
    // exponent field -> ~48% of samples have exponent > 0x85 (|v| > 64).
    // Genuine bf16 N(0,1) data essentially never does.
    unsigned e = (xw[tid] >> 7) & 0xFFu;
    s_cnt[tid] = (e > 0x85u) ? 1 : 0;
    __syncthreads();
    for (int s = 128; s > 0; s >>= 1) {
        if (tid < s) { s_or[tid] |= s_or[tid + s]; s_cnt[tid] += s_cnt[tid + s]; }
        __syncthreads();
    }
    if (tid == 0) {
        flags[0] = (s_or[0] == 0) ? 1 : 0;
        flags[1] = (s_cnt[0] >= 32) ? 1 : 0;
    }
}

// Canonicalize x -> bf16 (copy if already bf16, convert if fp32).
__global__ __launch_bounds__(256) void conv_x_kernel(
    const void* __restrict__ x, const int* __restrict__ flags,
    unsigned short* __restrict__ xb) {
    int t = blockIdx.x * 256 + threadIdx.x;
    if (t >= NN * 64) return;
    if (flags[1]) xb[t] = f2b(((const float*)x)[t]);
    else          xb[t] = ((const unsigned short*)x)[t];
}

// Build combined transposed bf16 weights + fp32 biases in global memory.
// Wt1g[c*128+k]: k<64 -> W1n[k,c]; k>=64 -> W1r[k-64,c]+Wl1[k-64,c]   (c<128)
// Wt2g[c*128+k]: c<64 -> W2n[k,c]; c>=64 -> W2r[k,c-64]+Wl2[k,c-64]   (k<128)
__global__ __launch_bounds__(256) void prep_w_kernel(
    const int* __restrict__ flags,
    const void* W1n, const void* W1r, const void* Wl1,
    const void* b1n, const void* bl1,
    const void* W2n, const void* W2r, const void* Wl2,
    const void* b2n, const void* bl2,
    unsigned short* __restrict__ Wt1g, unsigned short* __restrict__ Wt2g,
    float* __restrict__ bias1, float* __restrict__ bias2) {
    bool fp32 = flags[1] != 0;
    auto rd = [&](const void* p, int i) -> float {
        return fp32 ? ((const float*)p)[i] : b2f(((const unsigned short*)p)[i]);
    };
    int tid = threadIdx.x;
    if (blockIdx.x == 0) {
        for (int idx = tid; idx < 128 * 128; idx += 256) {
            int k = idx >> 7, c = idx & 127;
            float v = (k < 64) ? rd(W1n, k * 128 + c)
                               : rd(W1r, (k - 64) * 128 + c) + rd(Wl1, (k - 64) * 128 + c);
            Wt1g[c * 128 + k] = f2b(v);
        }
        for (int c = tid; c < 128; c += 256) bias1[c] = rd(b1n, c) + rd(bl1, c);
    } else {
        for (int idx = tid; idx < 128 * 128; idx += 256) {
            int k = idx >> 7, c = idx & 127;
            float v = (c < 64) ? rd(W2n, k * 64 + c)
                               : rd(W2r, k * 64 + (c - 64)) + rd(Wl2, k * 64 + (c - 64));
            Wt2g[c * 128 + k] = f2b(v);
        }
        for (int c = tid; c < 64; c += 256) bias2[c] = rd(b2n, c) + rd(bl2, c);
    }
}

// 16 threads per edge, each handles 4 consecutive bf16 features (8B load,
// 4 fp32 global atomics). feat is [NN,64] bf16 row-major.
__global__ __launch_bounds__(256) void edge_kernel(
    const unsigned short* __restrict__ feat, const int* __restrict__ ei,
    const int* __restrict__ flags, float* __restrict__ agg,
    float* __restrict__ deg) {
    unsigned int t = blockIdx.x * 256u + threadIdx.x;
    unsigned int e = t >> 4;
    unsigned int sub = t & 15u;
    if (e >= NE) return;
    int s, d;
    if (flags[0]) {
        const long long* ei64 = (const long long*)ei;
        s = (int)ei64[e];
        d = (int)ei64[NE + e];
    } else {
        s = ei[e];
        d = ei[NE + e];
    }
    const ushort4* vp = (const ushort4*)(feat + (size_t)s * 64 + sub * 4);
    ushort4 v = *vp;
    float* ap = agg + (size_t)d * 64 + sub * 4;
    atomicAdd(ap + 0, b2f(v.x));
    atomicAdd(ap + 1, b2f(v.y));
    atomicAdd(ap + 2, b2f(v.z));
    atomicAdd(ap + 3, b2f(v.w));
    if (deg != nullptr && sub == 0) atomicAdd(deg + d, 1.0f);
}

// GEMM1: h[N,128] = relu( [agg/deg | xb] @ Wt1g^T + bias1 )
// Block = 256 thr (4 waves), 64 rows/block, each wave: 16 rows x 128 cols
// via 8 accumulators of mfma_f32_16x16x32_bf16, K-loop of 4.
// Weights in LDS transposed with pitch 136 bf16 (16B-aligned, 2-way-free).
__global__ __launch_bounds__(256) void gemm1_kernel(
    const float* __restrict__ agg, const float* __restrict__ deg,
    const unsigned short* __restrict__ xb,
    const unsigned short* __restrict__ Wt1g, const float* __restrict__ bias1,
    unsigned short* __restrict__ h) {
    __shared__ unsigned short Wt[128 * 136];
    int tid = threadIdx.x;
    for (int idx = tid; idx < 2048; idx += 256) {   // 128 rows x 16 chunks of 8
        int c = idx >> 4, ch = idx & 15;
        *(bf16x8*)&Wt[c * 136 + ch * 8] = *(const bf16x8*)&Wt1g[c * 128 + ch * 8];
    }
    __syncthreads();

    int wid = tid >> 6, lane = tid & 63;
    int m = lane & 15, g = lane >> 4;
    int row0 = blockIdx.x * 64 + wid * 16;
    int arow = min(row0 + m, NN - 1);
    float rdeg = 1.0f / fmaxf(deg[arow], 1.0f);

    f32x4 acc[8];
#pragma unroll
    for (int nt = 0; nt < 8; ++nt) acc[nt] = (f32x4){0.f, 0.f, 0.f, 0.f};

#pragma unroll
    for (int kt = 0; kt < 4; ++kt) {
        int k0 = kt * 32 + g * 8;   // this lane's k-base (A[m][k0..k0+7])
        bf16x8 a;
        if (k0 < 64) {   // mean-aggregate half: fp32, scale by 1/deg, cvt bf16
            const float4* ap = (const float4*)(agg + (size_t)arow * 64 + k0);
            float4 a0 = ap[0], a1 = ap[1];
            a[0] = (__bf16)(a0.x * rdeg); a[1] = (__bf16)(a0.y * rdeg);
            a[2] = (__bf16)(a0.z * rdeg); a[3] = (__bf16)(a0.w * rdeg);
            a[4] = (__bf16)(a1.x * rdeg); a[5] = (__bf16)(a1.y * rdeg);
            a[6] = (__bf16)(a1.z * rdeg); a[7] = (__bf16)(a1.w * rdeg);
        } else {         // root-feature half: bf16 direct 16B load
            a = *(const bf16x8*)(xb + (size_t)arow * 64 + (k0 - 64));
        }
#pragma unroll
        for (int nt = 0; nt < 8; ++nt) {
            bf16x8 b = *(const bf16x8*)(&Wt[(nt * 16 + m) * 136 + k0]);
            acc[nt] = __builtin_amdgcn_mfma_f32_16x16x32_bf16(a, b, acc[nt], 0, 0, 0);
        }
    }

#pragma unroll
    for (int nt = 0; nt < 8; ++nt) {
        int col = nt * 16 + m;
        float bias = bias1[col];
#pragma unroll
        for (int r = 0; r < 4; ++r) {
            int row = row0 + g * 4 + r;   // C/D: row=(lane>>4)*4+reg, col=lane&15
            if (row < NN) {
                float v = fmaxf(acc[nt][r] + bias, 0.0f);
                h[(size_t)row * 128 + col] = f2b(v);
            }
        }
    }
}

// GEMM2: cols 0..63 -> p = h@W2n (bf16, gets scattered), cols 64..127 ->
// sf = h@(W2r+Wl2) (fp32, consumed by final kernel).
__global__ __launch_bounds__(256) void gemm2_kernel(
    const unsigned short* __restrict__ h,
    const unsigned short* __restrict__ Wt2g,
    unsigned short* __restrict__ p, float* __restrict__ sf) {
    __shared__ unsigned short Wt[128 * 136];
    int tid = threadIdx.x;
    for (int idx = tid; idx < 2048; idx += 256) {
        int c = idx >> 4, ch = idx & 15;
        *(bf16x8*)&Wt[c * 136 + ch * 8] = *(const bf16x8*)&Wt2g[c * 128 + ch * 8];
    }
    __syncthreads();

    int wid = tid >> 6, lane = tid & 63;
    int m = lane & 15, g = lane >> 4;
    int row0 = blockIdx.x * 64 + wid * 16;
    int arow = min(row0 + m, NN - 1);

    f32x4 acc[8];
#pragma unroll
    for (int nt = 0; nt < 8; ++nt) acc[nt] = (f32x4){0.f, 0.f, 0.f, 0.f};

#pragma unroll
    for (int kt = 0; kt < 4; ++kt) {
        int k0 = kt * 32 + g * 8;
        bf16x8 a = *(const bf16x8*)(h + (size_t)arow * 128 + k0);
#pragma unroll
        for (int nt = 0; nt < 8; ++nt) {
            bf16x8 b = *(const bf16x8*)(&Wt[(nt * 16 + m) * 136 + k0]);
            acc[nt] = __builtin_amdgcn_mfma_f32_16x16x32_bf16(a, b, acc[nt], 0, 0, 0);
        }
    }

#pragma unroll
    for (int nt = 0; nt < 8; ++nt) {
        int col = nt * 16 + m;
#pragma unroll
        for (int r = 0; r < 4; ++r) {
            int row = row0 + g * 4 + r;
            if (row < NN) {
                float v = acc[nt][r];
                if (col < 64) p[(size_t)row * 64 + col] = f2b(v);
                else          sf[(size_t)row * 64 + (col - 64)] = v;
            }
        }
    }
}

__global__ __launch_bounds__(256) void final_kernel(
    const float* __restrict__ agg, const float* __restrict__ deg,
    const float* __restrict__ sf, const float* __restrict__ bias2,
    const int* __restrict__ flags, void* __restrict__ out) {
    int t = blockIdx.x * 256 + threadIdx.x;
    if (t >= NN * 64) return;
    int i = t >> 6, f = t & 63;
    float degv = fmaxf(deg[i], 1.0f);
    float v = agg[t] / degv + sf[t] + bias2[f];
    if (flags[1]) ((float*)out)[t] = v;               // fp32 in -> fp32 out
    else          ((unsigned short*)out)[t] = f2b(v); // bf16 in -> bf16 out
}

extern "C" void kernel_launch(void* const* d_in, const int* in_sizes, int n_in,
                              void* d_out, int out_size, void* d_ws, size_t ws_size,
                              hipStream_t stream) {
    const void* x   = d_in[0];
    const int*  ei  = (const int*)d_in[1];
    const void* W1n = d_in[2];
    const void* b1n = d_in[3];
    const void* W1r = d_in[4];
    const void* Wl1 = d_in[5];
    const void* bl1 = d_in[6];
    const void* W2n = d_in[7];
    const void* b2n = d_in[8];
    const void* W2r = d_in[9];
    const void* Wl2 = d_in[10];
    const void* bl2 = d_in[11];

    char* ws = (char*)d_ws;
    // layout (total ~86 MiB); p reuses xb's region (xb dead after gemm1)
    int*            flags = (int*)(ws + 0);                    //      64 B
    float*          deg   = (float*)(ws + 1024);               // 400,000 B
    float*          bias1 = (float*)(ws + 401408);             //     512 B
    float*          bias2 = (float*)(ws + 401920);             //     256 B
    unsigned short* Wt1g  = (unsigned short*)(ws + 402432);    //  32,768 B
    unsigned short* Wt2g  = (unsigned short*)(ws + 435200);    //  32,768 B
    unsigned short* xb    = (unsigned short*)(ws + 467968);    // 12,800,000 B
    unsigned short* p     = xb;                                // (reused)
    float*          agg   = (float*)(ws + 13267968);           // 25,600,000 B
    unsigned short* h     = (unsigned short*)(ws + 38867968);  // 25,600,000 B
    float*          sf    = (float*)(ws + 64467968);           // 25,600,000 B

    (void)in_sizes; (void)n_in; (void)out_size; (void)ws_size;

    sniff_kernel<<<1, 256, 0, stream>>>(ei, (const unsigned int*)x, flags);
    conv_x_kernel<<<(NN * 64) / 256, 256, 0, stream>>>(x, flags, xb);
    prep_w_kernel<<<2, 256, 0, stream>>>(flags, W1n, W1r, Wl1, b1n, bl1,
                                         W2n, W2r, Wl2, b2n, bl2,
                                         Wt1g, Wt2g, bias1, bias2);
    hipMemsetAsync(deg, 0, 400000, stream);
    hipMemsetAsync(agg, 0, 25600000, stream);
    // layer 1 aggregation: agg += xb[src], deg += 1 at dst
    edge_kernel<<<(NE * 16) / 256, 256, 0, stream>>>(xb, ei, flags, agg, deg);
    gemm1_kernel<<<(NN + 63) / 64, 256, 0, stream>>>(agg, deg, xb, Wt1g, bias1, h);
    gemm2_kernel<<<(NN + 63) / 64, 256, 0, stream>>>(h, Wt2g, p, sf);
    // layer 2 aggregation of projected features (64-wide)
    hipMemsetAsync(agg, 0, 25600000, stream);
    edge_kernel<<<(NE * 16) / 256, 256, 0, stream>>>(p, ei, flags, agg, nullptr);
    final_kernel<<<(NN * 64) / 256, 256, 0, stream>>>(agg, deg, sf, bias2, flags, d_out);
}

// Round 3
// 689.677 us; speedup vs baseline: 4.2873x; 4.2873x over previous
//
#include <hip/hip_runtime.h>

// GNN_41051297415239: 2-layer GraphSAGE + linear skip on MI355X (gfx950)
// N=100000 nodes, E=1600000 edges, F_IN=64, HID=128, OUT=64
//
// R2 -> R3: replace atomic scatter-add aggregation (102M fp32 atomics/pass,
// 1.69 GB HBM write-thrash, 1425us/pass) with CSR-by-dst + gather:
//   hist (1.6M 4B atomics) -> single-block scan -> scatter (1.6M) ... once
//   agg = per-dst wave gather over csr_src, lane = feature, fp32 reg acc.
// Fusions: agg1 emits bf16 mean directly; agg2 fuses the final epilogue.
//
// Algebra:
//   h   = relu( [mean1 | x] @ [W1n ; W1r+Wl1] + (b1n+bl1) )   (K=128 GEMM)
//   p   = h @ W2n        (project BEFORE aggregating: 64-wide gather)
//   out = mean(p) + h @ (W2r+Wl2) + (b2n+bl2)

#define NN 100000
#define NE 1600000

typedef __attribute__((ext_vector_type(8))) __bf16 bf16x8;
typedef __attribute__((ext_vector_type(4))) float f32x4;

__device__ __forceinline__ float b2f(unsigned short u) {
    unsigned v = ((unsigned)u) << 16;
    float f;
    __builtin_memcpy(&f, &v, 4);
    return f;
}
__device__ __forceinline__ unsigned short f2b(float f) {
    unsigned u;
    __builtin_memcpy(&u, &f, 4);
    u += 0x7FFFu + ((u >> 16) & 1u);   // round-to-nearest-even
    return (unsigned short)(u >> 16);
}

// flags[0] = 1 if edge_index is int64; flags[1] = 1 if x/weights are fp32.
__global__ void sniff_kernel(const int* __restrict__ ei,
                             const unsigned int* __restrict__ xw,
                             int* __restrict__ flags) {
    __shared__ int s_or[256];
    __shared__ int s_cnt[256];
    int tid = threadIdx.x;
    s_or[tid] = ei[2 * tid + 1];
    unsigned e = (xw[tid] >> 7) & 0xFFu;
    s_cnt[tid] = (e > 0x85u) ? 1 : 0;
    __syncthreads();
    for (int s = 128; s > 0; s >>= 1) {
        if (tid < s) { s_or[tid] |= s_or[tid + s]; s_cnt[tid] += s_cnt[tid + s]; }
        __syncthreads();
    }
    if (tid == 0) {
        flags[0] = (s_or[0] == 0) ? 1 : 0;
        flags[1] = (s_cnt[0] >= 32) ? 1 : 0;
    }
}

// Canonicalize x -> bf16 (copy if already bf16, convert if fp32).
__global__ __launch_bounds__(256) void conv_x_kernel(
    const void* __restrict__ x, const int* __restrict__ flags,
    unsigned short* __restrict__ xb) {
    int t = blockIdx.x * 256 + threadIdx.x;
    if (t >= NN * 64) return;
    if (flags[1]) xb[t] = f2b(((const float*)x)[t]);
    else          xb[t] = ((const unsigned short*)x)[t];
}

// Combined transposed bf16 weights + fp32 biases.
__global__ __launch_bounds__(256) void prep_w_kernel(
    const int* __restrict__ flags,
    const void* W1n, const void* W1r, const void* Wl1,
    const void* b1n, const void* bl1,
    const void* W2n, const void* W2r, const void* Wl2,
    const void* b2n, const void* bl2,
    unsigned short* __restrict__ Wt1g, unsigned short* __restrict__ Wt2g,
    float* __restrict__ bias1, float* __restrict__ bias2) {
    bool fp32 = flags[1] != 0;
    auto rd = [&](const void* p, int i) -> float {
        return fp32 ? ((const float*)p)[i] : b2f(((const unsigned short*)p)[i]);
    };
    int tid = threadIdx.x;
    if (blockIdx.x == 0) {
        for (int idx = tid; idx < 128 * 128; idx += 256) {
            int k = idx >> 7, c = idx & 127;
            float v = (k < 64) ? rd(W1n, k * 128 + c)
                               : rd(W1r, (k - 64) * 128 + c) + rd(Wl1, (k - 64) * 128 + c);
            Wt1g[c * 128 + k] = f2b(v);
        }
        for (int c = tid; c < 128; c += 256) bias1[c] = rd(b1n, c) + rd(bl1, c);
    } else {
        for (int idx = tid; idx < 128 * 128; idx += 256) {
            int k = idx >> 7, c = idx & 127;
            float v = (c < 64) ? rd(W2n, k * 64 + c)
                               : rd(W2r, k * 64 + (c - 64)) + rd(Wl2, k * 64 + (c - 64));
            Wt2g[c * 128 + k] = f2b(v);
        }
        for (int c = tid; c < 64; c += 256) bias2[c] = rd(b2n, c) + rd(bl2, c);
    }
}

// --- CSR construction (built once, used for both aggregation passes) ---

__global__ __launch_bounds__(256) void hist_kernel(
    const int* __restrict__ ei, const int* __restrict__ flags,
    int* __restrict__ cnt) {
    int e = blockIdx.x * 256 + threadIdx.x;
    if (e >= NE) return;
    int d = flags[0] ? ei[2 * (NE + e)] : ei[NE + e];
    atomicAdd(&cnt[d], 1);
}

// Single-block exclusive scan of cnt[0..NN) -> row[], and cursor[]=row[].
#define SCAN_T 1024
__global__ __launch_bounds__(SCAN_T) void scan_kernel(
    int* __restrict__ cnt /* in: counts, out: cursor */, int* __restrict__ row) {
    __shared__ int part[SCAN_T];
    int t = threadIdx.x;
    const int chunk = (NN + SCAN_T - 1) / SCAN_T;   // 98
    int lo = t * chunk;
    int hi = min(lo + chunk, NN);
    int s = 0;
    for (int i = lo; i < hi; ++i) s += cnt[i];
    part[t] = s;
    __syncthreads();
    for (int off = 1; off < SCAN_T; off <<= 1) {    // Hillis-Steele inclusive
        int v = part[t];
        int add = (t >= off) ? part[t - off] : 0;
        __syncthreads();
        part[t] = v + add;
        __syncthreads();
    }
    int run = (t == 0) ? 0 : part[t - 1];
    for (int i = lo; i < hi; ++i) {
        int c = cnt[i];
        row[i] = run;
        cnt[i] = run;   // becomes the scatter cursor
        run += c;
    }
    if (t == SCAN_T - 1) row[NN] = run;             // = NE
}

__global__ __launch_bounds__(256) void scatter_kernel(
    const int* __restrict__ ei, const int* __restrict__ flags,
    int* __restrict__ cursor, int* __restrict__ csr) {
    int e = blockIdx.x * 256 + threadIdx.x;
    if (e >= NE) return;
    int s, d;
    if (flags[0]) { s = ei[2 * e]; d = ei[2 * (NE + e)]; }
    else          { s = ei[e];     d = ei[NE + e]; }
    int pos = atomicAdd(&cursor[d], 1);
    csr[pos] = s;
}

// --- Gather aggregation: one wave per dst node, lane = feature (64) ---
// feat: [NN,64] bf16. acc in fp32 registers; 4-way unrolled independent loads.

__device__ __forceinline__ float gather_mean(
    const unsigned short* __restrict__ feat, const int* __restrict__ row,
    const int* __restrict__ csr, int d, int lane, int* deg_out) {
    int base = row[d];
    int deg = row[d + 1] - base;
    *deg_out = deg;
    float acc = 0.f;
    for (int j0 = 0; j0 < deg; j0 += 64) {
        int cnt = min(64, deg - j0);
        int idx = (lane < cnt) ? csr[base + j0 + lane] : 0;
        int j = 0;
        for (; j + 4 <= cnt; j += 4) {
            int s0 = __shfl(idx, j + 0), s1 = __shfl(idx, j + 1);
            int s2 = __shfl(idx, j + 2), s3 = __shfl(idx, j + 3);
            float v0 = b2f(feat[(size_t)s0 * 64 + lane]);
            float v1 = b2f(feat[(size_t)s1 * 64 + lane]);
            float v2 = b2f(feat[(size_t)s2 * 64 + lane]);
            float v3 = b2f(feat[(size_t)s3 * 64 + lane]);
            acc += (v0 + v1) + (v2 + v3);
        }
        for (; j < cnt; ++j) {
            int s = __shfl(idx, j);
            acc += b2f(feat[(size_t)s * 64 + lane]);
        }
    }
    return acc / fmaxf((float)deg, 1.0f);
}

// Layer-1 aggregation: write bf16 mean1[N,64].
__global__ __launch_bounds__(256) void agg1_kernel(
    const unsigned short* __restrict__ feat, const int* __restrict__ row,
    const int* __restrict__ csr, unsigned short* __restrict__ mean1) {
    int wid = threadIdx.x >> 6, lane = threadIdx.x & 63;
    int d = blockIdx.x * 4 + wid;
    if (d >= NN) return;
    int deg;
    float m = gather_mean(feat, row, csr, d, lane, &deg);
    mean1[(size_t)d * 64 + lane] = f2b(m);
}

// Layer-2 aggregation fused with final epilogue:
// out = mean(p) + sf + bias2  (store fp32 or bf16 per flags[1]).
__global__ __launch_bounds__(256) void agg2_kernel(
    const unsigned short* __restrict__ p, const int* __restrict__ row,
    const int* __restrict__ csr, const float* __restrict__ sf,
    const float* __restrict__ bias2, const int* __restrict__ flags,
    void* __restrict__ out) {
    int wid = threadIdx.x >> 6, lane = threadIdx.x & 63;
    int d = blockIdx.x * 4 + wid;
    if (d >= NN) return;
    int deg;
    float m = gather_mean(p, row, csr, d, lane, &deg);
    float v = m + sf[(size_t)d * 64 + lane] + bias2[lane];
    if (flags[1]) ((float*)out)[(size_t)d * 64 + lane] = v;
    else          ((unsigned short*)out)[(size_t)d * 64 + lane] = f2b(v);
}

// GEMM1: h[N,128] = relu( [mean1 | xb] @ Wt1g^T + bias1 )
__global__ __launch_bounds__(256) void gemm1_kernel(
    const unsigned short* __restrict__ mean1,
    const unsigned short* __restrict__ xb,
    const unsigned short* __restrict__ Wt1g, const float* __restrict__ bias1,
    unsigned short* __restrict__ h) {
    __shared__ unsigned short Wt[128 * 136];
    int tid = threadIdx.x;
    for (int idx = tid; idx < 2048; idx += 256) {
        int c = idx >> 4, ch = idx & 15;
        *(bf16x8*)&Wt[c * 136 + ch * 8] = *(const bf16x8*)&Wt1g[c * 128 + ch * 8];
    }
    __syncthreads();

    int wid = tid >> 6, lane = tid & 63;
    int m = lane & 15, g = lane >> 4;
    int row0 = blockIdx.x * 64 + wid * 16;
    int arow = min(row0 + m, NN - 1);

    f32x4 acc[8];
#pragma unroll
    for (int nt = 0; nt < 8; ++nt) acc[nt] = (f32x4){0.f, 0.f, 0.f, 0.f};

#pragma unroll
    for (int kt = 0; kt < 4; ++kt) {
        int k0 = kt * 32 + g * 8;
        bf16x8 a = (k0 < 64)
            ? *(const bf16x8*)(mean1 + (size_t)arow * 64 + k0)
            : *(const bf16x8*)(xb + (size_t)arow * 64 + (k0 - 64));
#pragma unroll
        for (int nt = 0; nt < 8; ++nt) {
            bf16x8 b = *(const bf16x8*)(&Wt[(nt * 16 + m) * 136 + k0]);
            acc[nt] = __builtin_amdgcn_mfma_f32_16x16x32_bf16(a, b, acc[nt], 0, 0, 0);
        }
    }

#pragma unroll
    for (int nt = 0; nt < 8; ++nt) {
        int col = nt * 16 + m;
        float bias = bias1[col];
#pragma unroll
        for (int r = 0; r < 4; ++r) {
            int row = row0 + g * 4 + r;   // C/D: row=(lane>>4)*4+reg, col=lane&15
            if (row < NN) {
                float v = fmaxf(acc[nt][r] + bias, 0.0f);
                h[(size_t)row * 128 + col] = f2b(v);
            }
        }
    }
}

// GEMM2: cols 0..63 -> p = h@W2n (bf16), cols 64..127 -> sf = h@(W2r+Wl2) (fp32).
__global__ __launch_bounds__(256) void gemm2_kernel(
    const unsigned short* __restrict__ h,
    const unsigned short* __restrict__ Wt2g,
    unsigned short* __restrict__ p, float* __restrict__ sf) {
    __shared__ unsigned short Wt[128 * 136];
    int tid = threadIdx.x;
    for (int idx = tid; idx < 2048; idx += 256) {
        int c = idx >> 4, ch = idx & 15;
        *(bf16x8*)&Wt[c * 136 + ch * 8] = *(const bf16x8*)&Wt2g[c * 128 + ch * 8];
    }
    __syncthreads();

    int wid = tid >> 6, lane = tid & 63;
    int m = lane & 15, g = lane >> 4;
    int row0 = blockIdx.x * 64 + wid * 16;
    int arow = min(row0 + m, NN - 1);

    f32x4 acc[8];
#pragma unroll
    for (int nt = 0; nt < 8; ++nt) acc[nt] = (f32x4){0.f, 0.f, 0.f, 0.f};

#pragma unroll
    for (int kt = 0; kt < 4; ++kt) {
        int k0 = kt * 32 + g * 8;
        bf16x8 a = *(const bf16x8*)(h + (size_t)arow * 128 + k0);
#pragma unroll
        for (int nt = 0; nt < 8; ++nt) {
            bf16x8 b = *(const bf16x8*)(&Wt[(nt * 16 + m) * 136 + k0]);
            acc[nt] = __builtin_amdgcn_mfma_f32_16x16x32_bf16(a, b, acc[nt], 0, 0, 0);
        }
    }

#pragma unroll
    for (int nt = 0; nt < 8; ++nt) {
        int col = nt * 16 + m;
#pragma unroll
        for (int r = 0; r < 4; ++r) {
            int row = row0 + g * 4 + r;
            if (row < NN) {
                float v = acc[nt][r];
                if (col < 64) p[(size_t)row * 64 + col] = f2b(v);
                else          sf[(size_t)row * 64 + (col - 64)] = v;
            }
        }
    }
}

extern "C" void kernel_launch(void* const* d_in, const int* in_sizes, int n_in,
                              void* d_out, int out_size, void* d_ws, size_t ws_size,
                              hipStream_t stream) {
    const void* x   = d_in[0];
    const int*  ei  = (const int*)d_in[1];
    const void* W1n = d_in[2];
    const void* b1n = d_in[3];
    const void* W1r = d_in[4];
    const void* Wl1 = d_in[5];
    const void* bl1 = d_in[6];
    const void* W2n = d_in[7];
    const void* b2n = d_in[8];
    const void* W2r = d_in[9];
    const void* Wl2 = d_in[10];
    const void* bl2 = d_in[11];

    char* ws = (char*)d_ws;
    // total ~84.1 MB
    int*            flags  = (int*)(ws + 0);                    //      64 B
    int*            row    = (int*)(ws + 1024);                 // 400,004 B
    int*            cursor = (int*)(ws + 402432);               // 400,000 B
    float*          bias1  = (float*)(ws + 803840);             //     512 B
    float*          bias2  = (float*)(ws + 804352);             //     256 B
    unsigned short* Wt1g   = (unsigned short*)(ws + 804864);    //  32,768 B
    unsigned short* Wt2g   = (unsigned short*)(ws + 837632);    //  32,768 B
    int*            csr    = (int*)(ws + 870400);               // 6,400,000 B
    unsigned short* xb     = (unsigned short*)(ws + 7270400);   // 12,800,000 B
    unsigned short* p      = xb;                                // (xb dead after gemm1)
    unsigned short* mean1  = (unsigned short*)(ws + 20070400);  // 12,800,000 B
    unsigned short* h      = (unsigned short*)(ws + 32870400);  // 25,600,000 B
    float*          sf     = (float*)(ws + 58470400);           // 25,600,000 B

    (void)in_sizes; (void)n_in; (void)out_size; (void)ws_size;

    sniff_kernel<<<1, 256, 0, stream>>>(ei, (const unsigned int*)x, flags);
    conv_x_kernel<<<(NN * 64) / 256, 256, 0, stream>>>(x, flags, xb);
    prep_w_kernel<<<2, 256, 0, stream>>>(flags, W1n, W1r, Wl1, b1n, bl1,
                                         W2n, W2r, Wl2, b2n, bl2,
                                         Wt1g, Wt2g, bias1, bias2);
    // CSR build (once, shared by both layers)
    hipMemsetAsync(cursor, 0, 400000, stream);
    hist_kernel<<<(NE + 255) / 256, 256, 0, stream>>>(ei, flags, cursor);
    scan_kernel<<<1, SCAN_T, 0, stream>>>(cursor, row);
    scatter_kernel<<<(NE + 255) / 256, 256, 0, stream>>>(ei, flags, cursor, csr);
    // layer 1
    agg1_kernel<<<(NN + 3) / 4, 256, 0, stream>>>(xb, row, csr, mean1);
    gemm1_kernel<<<(NN + 63) / 64, 256, 0, stream>>>(mean1, xb, Wt1g, bias1, h);
    // layer 2
    gemm2_kernel<<<(NN + 63) / 64, 256, 0, stream>>>(h, Wt2g, p, sf);
    agg2_kernel<<<(NN + 3) / 4, 256, 0, stream>>>(p, row, csr, sf, bias2, flags, d_out);
}

// Round 4
// 469.139 us; speedup vs baseline: 6.3027x; 1.4701x over previous
//
#include <hip/hip_runtime.h>

// GNN_41051297415239: 2-layer GraphSAGE + linear skip on MI355X (gfx950)
// N=100000 nodes, E=1600000 edges, F_IN=64, HID=128, OUT=64
//
// R3 -> R4: the single-block scan_kernel was 233us (34% of total) at 0.148%
// occupancy -- pure latency on one CU. Replaced with a 3-kernel hierarchical
// scan (partial sums -> scan of 391 block sums -> per-block scan + offset).
//
// Pipeline: sniff -> conv_x -> prep_w -> hist -> scan(x3) -> scatter ->
//           agg1(gather mean) -> gemm1 -> gemm2 -> agg2(gather+epilogue).
//
// Algebra:
//   h   = relu( [mean1 | x] @ [W1n ; W1r+Wl1] + (b1n+bl1) )   (K=128 GEMM)
//   p   = h @ W2n        (project BEFORE aggregating: 64-wide gather)
//   out = mean(p) + h @ (W2r+Wl2) + (b2n+bl2)

#define NN 100000
#define NE 1600000
#define SCAN_NB 391   // ceil(NN/256)

typedef __attribute__((ext_vector_type(8))) __bf16 bf16x8;
typedef __attribute__((ext_vector_type(4))) float f32x4;

__device__ __forceinline__ float b2f(unsigned short u) {
    unsigned v = ((unsigned)u) << 16;
    float f;
    __builtin_memcpy(&f, &v, 4);
    return f;
}
__device__ __forceinline__ unsigned short f2b(float f) {
    unsigned u;
    __builtin_memcpy(&u, &f, 4);
    u += 0x7FFFu + ((u >> 16) & 1u);   // round-to-nearest-even
    return (unsigned short)(u >> 16);
}

// flags[0] = 1 if edge_index is int64; flags[1] = 1 if x/weights are fp32.
__global__ void sniff_kernel(const int* __restrict__ ei,
                             const unsigned int* __restrict__ xw,
                             int* __restrict__ flags) {
    __shared__ int s_or[256];
    __shared__ int s_cnt[256];
    int tid = threadIdx.x;
    s_or[tid] = ei[2 * tid + 1];
    unsigned e = (xw[tid] >> 7) & 0xFFu;
    s_cnt[tid] = (e > 0x85u) ? 1 : 0;
    __syncthreads();
    for (int s = 128; s > 0; s >>= 1) {
        if (tid < s) { s_or[tid] |= s_or[tid + s]; s_cnt[tid] += s_cnt[tid + s]; }
        __syncthreads();
    }
    if (tid == 0) {
        flags[0] = (s_or[0] == 0) ? 1 : 0;
        flags[1] = (s_cnt[0] >= 32) ? 1 : 0;
    }
}

// Canonicalize x -> bf16 (copy if already bf16, convert if fp32).
__global__ __launch_bounds__(256) void conv_x_kernel(
    const void* __restrict__ x, const int* __restrict__ flags,
    unsigned short* __restrict__ xb) {
    int t = blockIdx.x * 256 + threadIdx.x;
    if (t >= NN * 64) return;
    if (flags[1]) xb[t] = f2b(((const float*)x)[t]);
    else          xb[t] = ((const unsigned short*)x)[t];
}

// Combined transposed bf16 weights + fp32 biases.
__global__ __launch_bounds__(256) void prep_w_kernel(
    const int* __restrict__ flags,
    const void* W1n, const void* W1r, const void* Wl1,
    const void* b1n, const void* bl1,
    const void* W2n, const void* W2r, const void* Wl2,
    const void* b2n, const void* bl2,
    unsigned short* __restrict__ Wt1g, unsigned short* __restrict__ Wt2g,
    float* __restrict__ bias1, float* __restrict__ bias2) {
    bool fp32 = flags[1] != 0;
    auto rd = [&](const void* p, int i) -> float {
        return fp32 ? ((const float*)p)[i] : b2f(((const unsigned short*)p)[i]);
    };
    int tid = threadIdx.x;
    if (blockIdx.x == 0) {
        for (int idx = tid; idx < 128 * 128; idx += 256) {
            int k = idx >> 7, c = idx & 127;
            float v = (k < 64) ? rd(W1n, k * 128 + c)
                               : rd(W1r, (k - 64) * 128 + c) + rd(Wl1, (k - 64) * 128 + c);
            Wt1g[c * 128 + k] = f2b(v);
        }
        for (int c = tid; c < 128; c += 256) bias1[c] = rd(b1n, c) + rd(bl1, c);
    } else {
        for (int idx = tid; idx < 128 * 128; idx += 256) {
            int k = idx >> 7, c = idx & 127;
            float v = (c < 64) ? rd(W2n, k * 64 + c)
                               : rd(W2r, k * 64 + (c - 64)) + rd(Wl2, k * 64 + (c - 64));
            Wt2g[c * 128 + k] = f2b(v);
        }
        for (int c = tid; c < 64; c += 256) bias2[c] = rd(b2n, c) + rd(bl2, c);
    }
}

// --- CSR construction (built once, used for both aggregation passes) ---

__global__ __launch_bounds__(256) void hist_kernel(
    const int* __restrict__ ei, const int* __restrict__ flags,
    int* __restrict__ cnt) {
    int e = blockIdx.x * 256 + threadIdx.x;
    if (e >= NE) return;
    int d = flags[0] ? ei[2 * (NE + e)] : ei[NE + e];
    atomicAdd(&cnt[d], 1);
}

// Hierarchical scan, step 1: per-block (256-wide) sums of cnt -> bsum[SCAN_NB].
__global__ __launch_bounds__(256) void scan_part_kernel(
    const int* __restrict__ cnt, int* __restrict__ bsum) {
    __shared__ int s[256];
    int t = threadIdx.x;
    int i = blockIdx.x * 256 + t;
    s[t] = (i < NN) ? cnt[i] : 0;
    __syncthreads();
    for (int off = 128; off > 0; off >>= 1) {
        if (t < off) s[t] += s[t + off];
        __syncthreads();
    }
    if (t == 0) bsum[blockIdx.x] = s[0];
}

// Step 2: exclusive scan of the SCAN_NB block sums (single small block).
__global__ __launch_bounds__(512) void scan_mid_kernel(int* __restrict__ bsum) {
    __shared__ int s[512];
    int t = threadIdx.x;
    int v = (t < SCAN_NB) ? bsum[t] : 0;
    s[t] = v;
    __syncthreads();
    for (int off = 1; off < 512; off <<= 1) {
        int add = (t >= off) ? s[t - off] : 0;
        __syncthreads();
        s[t] += add;
        __syncthreads();
    }
    if (t < SCAN_NB) bsum[t] = s[t] - v;   // exclusive
}

// Step 3: per-block exclusive scan + block offset -> row[] and cursor[].
__global__ __launch_bounds__(256) void scan_final_kernel(
    int* __restrict__ cnt /* in: counts, out: cursor */,
    const int* __restrict__ bsum, int* __restrict__ row) {
    __shared__ int s[256];
    int t = threadIdx.x;
    int i = blockIdx.x * 256 + t;
    int v = (i < NN) ? cnt[i] : 0;
    s[t] = v;
    __syncthreads();
    for (int off = 1; off < 256; off <<= 1) {
        int add = (t >= off) ? s[t - off] : 0;
        __syncthreads();
        s[t] += add;
        __syncthreads();
    }
    int excl = s[t] - v + bsum[blockIdx.x];
    if (i < NN) { row[i] = excl; cnt[i] = excl; }
    if (i == NN - 1) row[NN] = excl + v;   // = NE
}

__global__ __launch_bounds__(256) void scatter_kernel(
    const int* __restrict__ ei, const int* __restrict__ flags,
    int* __restrict__ cursor, int* __restrict__ csr) {
    int e = blockIdx.x * 256 + threadIdx.x;
    if (e >= NE) return;
    int s, d;
    if (flags[0]) { s = ei[2 * e]; d = ei[2 * (NE + e)]; }
    else          { s = ei[e];     d = ei[NE + e]; }
    int pos = atomicAdd(&cursor[d], 1);
    csr[pos] = s;
}

// --- Gather aggregation: one wave per dst node, lane = feature (64) ---

__device__ __forceinline__ float gather_mean(
    const unsigned short* __restrict__ feat, const int* __restrict__ row,
    const int* __restrict__ csr, int d, int lane) {
    int base = row[d];
    int deg = row[d + 1] - base;
    float acc = 0.f;
    for (int j0 = 0; j0 < deg; j0 += 64) {
        int cnt = min(64, deg - j0);
        int idx = (lane < cnt) ? csr[base + j0 + lane] : 0;
        int j = 0;
        for (; j + 4 <= cnt; j += 4) {
            int s0 = __shfl(idx, j + 0), s1 = __shfl(idx, j + 1);
            int s2 = __shfl(idx, j + 2), s3 = __shfl(idx, j + 3);
            float v0 = b2f(feat[(size_t)s0 * 64 + lane]);
            float v1 = b2f(feat[(size_t)s1 * 64 + lane]);
            float v2 = b2f(feat[(size_t)s2 * 64 + lane]);
            float v3 = b2f(feat[(size_t)s3 * 64 + lane]);
            acc += (v0 + v1) + (v2 + v3);
        }
        for (; j < cnt; ++j) {
            int s = __shfl(idx, j);
            acc += b2f(feat[(size_t)s * 64 + lane]);
        }
    }
    return acc / fmaxf((float)deg, 1.0f);
}

// Layer-1 aggregation: write bf16 mean1[N,64].
__global__ __launch_bounds__(256) void agg1_kernel(
    const unsigned short* __restrict__ feat, const int* __restrict__ row,
    const int* __restrict__ csr, unsigned short* __restrict__ mean1) {
    int wid = threadIdx.x >> 6, lane = threadIdx.x & 63;
    int d = blockIdx.x * 4 + wid;
    if (d >= NN) return;
    float m = gather_mean(feat, row, csr, d, lane);
    mean1[(size_t)d * 64 + lane] = f2b(m);
}

// Layer-2 aggregation fused with final epilogue:
// out = mean(p) + sf + bias2  (store fp32 or bf16 per flags[1]).
__global__ __launch_bounds__(256) void agg2_kernel(
    const unsigned short* __restrict__ p, const int* __restrict__ row,
    const int* __restrict__ csr, const float* __restrict__ sf,
    const float* __restrict__ bias2, const int* __restrict__ flags,
    void* __restrict__ out) {
    int wid = threadIdx.x >> 6, lane = threadIdx.x & 63;
    int d = blockIdx.x * 4 + wid;
    if (d >= NN) return;
    float m = gather_mean(p, row, csr, d, lane);
    float v = m + sf[(size_t)d * 64 + lane] + bias2[lane];
    if (flags[1]) ((float*)out)[(size_t)d * 64 + lane] = v;
    else          ((unsigned short*)out)[(size_t)d * 64 + lane] = f2b(v);
}

// GEMM1: h[N,128] = relu( [mean1 | xb] @ Wt1g^T + bias1 )
__global__ __launch_bounds__(256) void gemm1_kernel(
    const unsigned short* __restrict__ mean1,
    const unsigned short* __restrict__ xb,
    const unsigned short* __restrict__ Wt1g, const float* __restrict__ bias1,
    unsigned short* __restrict__ h) {
    __shared__ unsigned short Wt[128 * 136];
    int tid = threadIdx.x;
    for (int idx = tid; idx < 2048; idx += 256) {
        int c = idx >> 4, ch = idx & 15;
        *(bf16x8*)&Wt[c * 136 + ch * 8] = *(const bf16x8*)&Wt1g[c * 128 + ch * 8];
    }
    __syncthreads();

    int wid = tid >> 6, lane = tid & 63;
    int m = lane & 15, g = lane >> 4;
    int row0 = blockIdx.x * 64 + wid * 16;
    int arow = min(row0 + m, NN - 1);

    f32x4 acc[8];
#pragma unroll
    for (int nt = 0; nt < 8; ++nt) acc[nt] = (f32x4){0.f, 0.f, 0.f, 0.f};

#pragma unroll
    for (int kt = 0; kt < 4; ++kt) {
        int k0 = kt * 32 + g * 8;
        bf16x8 a = (k0 < 64)
            ? *(const bf16x8*)(mean1 + (size_t)arow * 64 + k0)
            : *(const bf16x8*)(xb + (size_t)arow * 64 + (k0 - 64));
#pragma unroll
        for (int nt = 0; nt < 8; ++nt) {
            bf16x8 b = *(const bf16x8*)(&Wt[(nt * 16 + m) * 136 + k0]);
            acc[nt] = __builtin_amdgcn_mfma_f32_16x16x32_bf16(a, b, acc[nt], 0, 0, 0);
        }
    }

#pragma unroll
    for (int nt = 0; nt < 8; ++nt) {
        int col = nt * 16 + m;
        float bias = bias1[col];
#pragma unroll
        for (int r = 0; r < 4; ++r) {
            int row = row0 + g * 4 + r;   // C/D: row=(lane>>4)*4+reg, col=lane&15
            if (row < NN) {
                float v = fmaxf(acc[nt][r] + bias, 0.0f);
                h[(size_t)row * 128 + col] = f2b(v);
            }
        }
    }
}

// GEMM2: cols 0..63 -> p = h@W2n (bf16), cols 64..127 -> sf = h@(W2r+Wl2) (fp32).
__global__ __launch_bounds__(256) void gemm2_kernel(
    const unsigned short* __restrict__ h,
    const unsigned short* __restrict__ Wt2g,
    unsigned short* __restrict__ p, float* __restrict__ sf) {
    __shared__ unsigned short Wt[128 * 136];
    int tid = threadIdx.x;
    for (int idx = tid; idx < 2048; idx += 256) {
        int c = idx >> 4, ch = idx & 15;
        *(bf16x8*)&Wt[c * 136 + ch * 8] = *(const bf16x8*)&Wt2g[c * 128 + ch * 8];
    }
    __syncthreads();

    int wid = tid >> 6, lane = tid & 63;
    int m = lane & 15, g = lane >> 4;
    int row0 = blockIdx.x * 64 + wid * 16;
    int arow = min(row0 + m, NN - 1);

    f32x4 acc[8];
#pragma unroll
    for (int nt = 0; nt < 8; ++nt) acc[nt] = (f32x4){0.f, 0.f, 0.f, 0.f};

#pragma unroll
    for (int kt = 0; kt < 4; ++kt) {
        int k0 = kt * 32 + g * 8;
        bf16x8 a = *(const bf16x8*)(h + (size_t)arow * 128 + k0);
#pragma unroll
        for (int nt = 0; nt < 8; ++nt) {
            bf16x8 b = *(const bf16x8*)(&Wt[(nt * 16 + m) * 136 + k0]);
            acc[nt] = __builtin_amdgcn_mfma_f32_16x16x32_bf16(a, b, acc[nt], 0, 0, 0);
        }
    }

#pragma unroll
    for (int nt = 0; nt < 8; ++nt) {
        int col = nt * 16 + m;
#pragma unroll
        for (int r = 0; r < 4; ++r) {
            int row = row0 + g * 4 + r;
            if (row < NN) {
                float v = acc[nt][r];
                if (col < 64) p[(size_t)row * 64 + col] = f2b(v);
                else          sf[(size_t)row * 64 + (col - 64)] = v;
            }
        }
    }
}

extern "C" void kernel_launch(void* const* d_in, const int* in_sizes, int n_in,
                              void* d_out, int out_size, void* d_ws, size_t ws_size,
                              hipStream_t stream) {
    const void* x   = d_in[0];
    const int*  ei  = (const int*)d_in[1];
    const void* W1n = d_in[2];
    const void* b1n = d_in[3];
    const void* W1r = d_in[4];
    const void* Wl1 = d_in[5];
    const void* bl1 = d_in[6];
    const void* W2n = d_in[7];
    const void* b2n = d_in[8];
    const void* W2r = d_in[9];
    const void* Wl2 = d_in[10];
    const void* bl2 = d_in[11];

    char* ws = (char*)d_ws;
    // total ~84.1 MB
    int*            flags  = (int*)(ws + 0);                    //      64 B
    int*            row    = (int*)(ws + 1024);                 // 400,004 B
    int*            cursor = (int*)(ws + 402432);               // 400,000 B
    int*            bsum   = (int*)(ws + 802432);               //   1,564 B
    float*          bias1  = (float*)(ws + 804352);             //     512 B
    float*          bias2  = (float*)(ws + 804864);             //     256 B
    unsigned short* Wt1g   = (unsigned short*)(ws + 805376);    //  32,768 B
    unsigned short* Wt2g   = (unsigned short*)(ws + 838144);    //  32,768 B
    int*            csr    = (int*)(ws + 870912);               // 6,400,000 B
    unsigned short* xb     = (unsigned short*)(ws + 7270912);   // 12,800,000 B
    unsigned short* p      = xb;                                // (xb dead after gemm1)
    unsigned short* mean1  = (unsigned short*)(ws + 20070912);  // 12,800,000 B
    unsigned short* h      = (unsigned short*)(ws + 32870912);  // 25,600,000 B
    float*          sf     = (float*)(ws + 58470912);           // 25,600,000 B

    (void)in_sizes; (void)n_in; (void)out_size; (void)ws_size;

    sniff_kernel<<<1, 256, 0, stream>>>(ei, (const unsigned int*)x, flags);
    conv_x_kernel<<<(NN * 64) / 256, 256, 0, stream>>>(x, flags, xb);
    prep_w_kernel<<<2, 256, 0, stream>>>(flags, W1n, W1r, Wl1, b1n, bl1,
                                         W2n, W2r, Wl2, b2n, bl2,
                                         Wt1g, Wt2g, bias1, bias2);
    // CSR build (once, shared by both layers)
    hipMemsetAsync(cursor, 0, 400000, stream);
    hist_kernel<<<(NE + 255) / 256, 256, 0, stream>>>(ei, flags, cursor);
    scan_part_kernel<<<SCAN_NB, 256, 0, stream>>>(cursor, bsum);
    scan_mid_kernel<<<1, 512, 0, stream>>>(bsum);
    scan_final_kernel<<<SCAN_NB, 256, 0, stream>>>(cursor, bsum, row);
    scatter_kernel<<<(NE + 255) / 256, 256, 0, stream>>>(ei, flags, cursor, csr);
    // layer 1
    agg1_kernel<<<(NN + 3) / 4, 256, 0, stream>>>(xb, row, csr, mean1);
    gemm1_kernel<<<(NN + 63) / 64, 256, 0, stream>>>(mean1, xb, Wt1g, bias1, h);
    // layer 2
    gemm2_kernel<<<(NN + 63) / 64, 256, 0, stream>>>(h, Wt2g, p, sf);
    agg2_kernel<<<(NN + 3) / 4, 256, 0, stream>>>(p, row, csr, sf, bias2, flags, d_out);
}